// Round 2
// baseline (15335.342 us; speedup 1.0000x reference)
//
#include <hip/hip_runtime.h>
#include <cmath>

#define B_ 256
#define T_ 256
#define F_ 40
#define H_ 256
#define A_ 64
#define HOR_ 60
#define DSP_ 192

typedef unsigned short u16;
typedef unsigned int u32;
typedef __attribute__((ext_vector_type(8))) short bf16x8;
typedef __attribute__((ext_vector_type(4))) float f32x4;
typedef __attribute__((ext_vector_type(8))) u32 u32x8;

__device__ __forceinline__ float sigm(float x){ return 1.f/(1.f+expf(-x)); }

__device__ __forceinline__ u16 f2bf(float x){
  u32 u = __float_as_uint(x);
  u32 r = (u + 0x7FFFu + ((u>>16)&1u)) >> 16;
  return (u16)r;
}
__device__ __forceinline__ float bf2f(u16 h){ return __uint_as_float(((u32)h)<<16); }
__device__ __forceinline__ u32 packsplit(float x){
  u16 hi = f2bf(x);
  u16 lo = f2bf(x - bf2f(hi));
  return (u32)hi | ((u32)lo<<16);
}
// hi in low16, lo in high16
__device__ __forceinline__ float unpack2f(u32 v){
  return __uint_as_float(v<<16) + __uint_as_float(v & 0xFFFF0000u);
}

__device__ __forceinline__ float wred_sum(float v){
  #pragma unroll
  for (int o=32;o>0;o>>=1) v += __shfl_xor(v,o);
  return v;
}
__device__ __forceinline__ float wred_max(float v){
  #pragma unroll
  for (int o=32;o>0;o>>=1) v = fmaxf(v,__shfl_xor(v,o));
  return v;
}

// ---- weight conversion: dst[n][k] (hi/lo bf16) = src[k][n], src = [Wx ; Wh] ----
__global__ void conv_w(const float* __restrict__ Wx, const float* __restrict__ Wh,
                       u16* __restrict__ hi, u16* __restrict__ lo,
                       int KX, int Ktot, int N){
  int idx = blockIdx.x*256 + threadIdx.x;
  if (idx >= N*Ktot) return;
  int n = idx / Ktot, k = idx - n*Ktot;
  float w = (k < KX) ? Wx[(size_t)k*N + n] : Wh[(size_t)(k-KX)*N + n];
  u16 h = f2bf(w);
  hi[idx] = h;
  lo[idx] = f2bf(w - bf2f(h));
}

// ---- spatial projection: hsp[t][b][192] (hi/lo) = x[b][t][:40] @ W_sp + b_sp ----
__global__ __launch_bounds__(256) void spatial_proj(
    const float* __restrict__ x, const float* __restrict__ W, const float* __restrict__ bsp,
    u16* __restrict__ hi, u16* __restrict__ lo){
  int b = blockIdx.x, t = threadIdx.x;
  float4 xv[10];
  const float4* xp = (const float4*)(x + ((size_t)b*T_ + t)*F_);
  #pragma unroll
  for (int i=0;i<10;i++) xv[i] = xp[i];
  for (int c=0;c<DSP_;c++){
    float acc = bsp[c];
    #pragma unroll
    for (int k=0;k<F_;k++)
      acc += ((const float*)xv)[k] * W[k*DSP_ + c];
    size_t o = ((size_t)t*B_ + b)*DSP_ + c;
    u16 h = f2bf(acc);
    hi[o] = h;
    lo[o] = f2bf(acc - bf2f(h));
  }
}

// ---- encoder step (both dirs), MFMA split-bf16, cell fused in registers ----
// W layout [dir][n=g*256+u][448], A = [hsp_t(192) | h(256)]
__global__ __launch_bounds__(256) void enc_step_mfma(
    const u16* __restrict__ hsp_hi, const u16* __restrict__ hsp_lo,
    const u16* __restrict__ W_hi, const u16* __restrict__ W_lo,
    const float* __restrict__ b_ef, const float* __restrict__ b_eb,
    const u16* __restrict__ hin_hi, const u16* __restrict__ hin_lo,
    u16* __restrict__ hout_hi, u16* __restrict__ hout_lo,
    float* __restrict__ c_enc, u32* __restrict__ eo32, int s)
{
  const int dir = blockIdx.y;
  const int t = dir ? (T_-1-s) : s;
  const int u0 = blockIdx.x * 16;
  const int tid = threadIdx.x;
  const int wave = tid >> 6, lane = tid & 63;
  const int lrow = lane & 15, kblk = lane >> 4;
  const int u = u0 + lrow;
  const int mbase = wave * 64;
  const int koff = kblk * 8;
  const float* bias = dir ? b_eb : b_ef;
  const u16* Wh = W_hi + (size_t)dir*1024*448;
  const u16* Wl = W_lo + (size_t)dir*1024*448;

  size_t wro[4];
  #pragma unroll
  for (int g=0; g<4; g++) wro[g] = (size_t)(g*H_ + u) * 448;

  f32x4 acc[4][4] = {};

  // K part 1: hsp (k 0..191)
  for (int ks=0; ks<6; ks++){
    int kb = ks*32 + koff;
    bf16x8 ah[4], al[4], bh[4], bl[4];
    #pragma unroll
    for (int mf=0; mf<4; mf++){
      int br = mbase + mf*16 + lrow;
      size_t o = ((size_t)t*B_ + br)*DSP_ + kb;
      ah[mf] = *(const bf16x8*)(hsp_hi + o);
      al[mf] = *(const bf16x8*)(hsp_lo + o);
    }
    #pragma unroll
    for (int g=0; g<4; g++){
      bh[g] = *(const bf16x8*)(Wh + wro[g] + kb);
      bl[g] = *(const bf16x8*)(Wl + wro[g] + kb);
    }
    #pragma unroll
    for (int mf=0; mf<4; mf++)
      #pragma unroll
      for (int g=0; g<4; g++){
        acc[mf][g] = __builtin_amdgcn_mfma_f32_16x16x32_bf16(ah[mf], bh[g], acc[mf][g], 0,0,0);
        acc[mf][g] = __builtin_amdgcn_mfma_f32_16x16x32_bf16(ah[mf], bl[g], acc[mf][g], 0,0,0);
        acc[mf][g] = __builtin_amdgcn_mfma_f32_16x16x32_bf16(al[mf], bh[g], acc[mf][g], 0,0,0);
      }
  }
  // K part 2: h (k 192..447)
  for (int ks=0; ks<8; ks++){
    int kb = ks*32 + koff;
    bf16x8 ah[4], al[4], bh[4], bl[4];
    #pragma unroll
    for (int mf=0; mf<4; mf++){
      int br = mbase + mf*16 + lrow;
      size_t o = ((size_t)dir*B_ + br)*H_ + kb;
      ah[mf] = *(const bf16x8*)(hin_hi + o);
      al[mf] = *(const bf16x8*)(hin_lo + o);
    }
    #pragma unroll
    for (int g=0; g<4; g++){
      bh[g] = *(const bf16x8*)(Wh + wro[g] + 192 + kb);
      bl[g] = *(const bf16x8*)(Wl + wro[g] + 192 + kb);
    }
    #pragma unroll
    for (int mf=0; mf<4; mf++)
      #pragma unroll
      for (int g=0; g<4; g++){
        acc[mf][g] = __builtin_amdgcn_mfma_f32_16x16x32_bf16(ah[mf], bh[g], acc[mf][g], 0,0,0);
        acc[mf][g] = __builtin_amdgcn_mfma_f32_16x16x32_bf16(ah[mf], bl[g], acc[mf][g], 0,0,0);
        acc[mf][g] = __builtin_amdgcn_mfma_f32_16x16x32_bf16(al[mf], bh[g], acc[mf][g], 0,0,0);
      }
  }
  // epilogue: bias + cell + writes
  float bg4[4];
  #pragma unroll
  for (int g=0;g<4;g++) bg4[g] = bias[g*H_ + u];
  #pragma unroll
  for (int mf=0; mf<4; mf++){
    #pragma unroll
    for (int r=0; r<4; r++){
      int b = mbase + mf*16 + kblk*4 + r;
      float gi = acc[mf][0][r] + bg4[0];
      float gf = acc[mf][1][r] + bg4[1];
      float gg = acc[mf][2][r] + bg4[2];
      float go = acc[mf][3][r] + bg4[3];
      size_t ci = ((size_t)dir*B_ + b)*H_ + u;
      float cn = sigm(gf)*c_enc[ci] + sigm(gi)*tanhf(gg);
      float hn = sigm(go)*tanhf(cn);
      c_enc[ci] = cn;
      u16 hh = f2bf(hn);
      u16 hl = f2bf(hn - bf2f(hh));
      hout_hi[ci] = hh;
      hout_lo[ci] = hl;
      eo32[((size_t)b*T_ + t)*512 + dir*H_ + u] = (u32)hh | ((u32)hl<<16);
    }
  }
}

// ---- decoder LSTM step: A = Ad32 packed [b][768] = [context|h], + py rank-1 ----
__global__ __launch_bounds__(256) void dec_step_mfma(
    const u32* __restrict__ Ad32,
    const u16* __restrict__ W_hi, const u16* __restrict__ W_lo,
    const float* __restrict__ b_d, const float* __restrict__ Wx_d,
    const float* __restrict__ py,
    float* __restrict__ c_dec, float* __restrict__ h_dec,
    u32* __restrict__ AdW)
{
  const int u0 = blockIdx.x * 16;
  const int tid = threadIdx.x;
  const int wave = tid >> 6, lane = tid & 63;
  const int lrow = lane & 15, kblk = lane >> 4;
  const int u = u0 + lrow;
  const int mbase = wave * 64;
  const int koff = kblk * 8;

  size_t wro[4];
  #pragma unroll
  for (int g=0; g<4; g++) wro[g] = (size_t)(g*H_ + u) * 768;

  f32x4 acc[4][4] = {};

  for (int ks=0; ks<24; ks++){
    int kb = ks*32 + koff;
    bf16x8 ah[4], al[4], bh[4], bl[4];
    #pragma unroll
    for (int mf=0; mf<4; mf++){
      int br = mbase + mf*16 + lrow;
      u32x8 ld = *(const u32x8*)(Ad32 + (size_t)br*768 + kb);
      bf16x8 h8, l8;
      #pragma unroll
      for (int j=0;j<8;j++){ h8[j] = (short)(ld[j] & 0xFFFFu); l8[j] = (short)(ld[j] >> 16); }
      ah[mf] = h8; al[mf] = l8;
    }
    #pragma unroll
    for (int g=0; g<4; g++){
      bh[g] = *(const bf16x8*)(W_hi + wro[g] + kb);
      bl[g] = *(const bf16x8*)(W_lo + wro[g] + kb);
    }
    #pragma unroll
    for (int mf=0; mf<4; mf++)
      #pragma unroll
      for (int g=0; g<4; g++){
        acc[mf][g] = __builtin_amdgcn_mfma_f32_16x16x32_bf16(ah[mf], bh[g], acc[mf][g], 0,0,0);
        acc[mf][g] = __builtin_amdgcn_mfma_f32_16x16x32_bf16(ah[mf], bl[g], acc[mf][g], 0,0,0);
        acc[mf][g] = __builtin_amdgcn_mfma_f32_16x16x32_bf16(al[mf], bh[g], acc[mf][g], 0,0,0);
      }
  }
  float bg4[4], w0g[4];
  #pragma unroll
  for (int g=0;g<4;g++){ bg4[g] = b_d[g*H_ + u]; w0g[g] = Wx_d[g*H_ + u]; }
  #pragma unroll
  for (int mf=0; mf<4; mf++){
    #pragma unroll
    for (int r=0; r<4; r++){
      int b = mbase + mf*16 + kblk*4 + r;
      float pyb = py[b];
      float gi = acc[mf][0][r] + bg4[0] + pyb*w0g[0];
      float gf = acc[mf][1][r] + bg4[1] + pyb*w0g[1];
      float gg = acc[mf][2][r] + bg4[2] + pyb*w0g[2];
      float go = acc[mf][3][r] + bg4[3] + pyb*w0g[3];
      size_t ci = (size_t)b*H_ + u;
      float cn = sigm(gf)*c_dec[ci] + sigm(gi)*tanhf(gg);
      float hn = sigm(go)*tanhf(cn);
      c_dec[ci] = cn;
      h_dec[ci] = hn;
      AdW[(size_t)b*768 + 512 + u] = packsplit(hn);
    }
  }
}

// ---- enc_proj: ep[bt][64] = eo @ We, MFMA split ----
__global__ __launch_bounds__(256) void gemm_ep(
    const u32* __restrict__ eo32, const u16* __restrict__ Wet_hi, const u16* __restrict__ Wet_lo,
    float* __restrict__ ep)
{
  const int tid = threadIdx.x, wave = tid>>6, lane = tid&63;
  const int lrow = lane&15, kblk = lane>>4, koff = kblk*8;
  const size_t arow = (size_t)blockIdx.x*64 + wave*16 + lrow;
  f32x4 acc[4] = {};
  size_t wro[4];
  #pragma unroll
  for (int nf=0; nf<4; nf++) wro[nf] = (size_t)(nf*16 + lrow)*512;
  for (int ks=0; ks<16; ks++){
    int kb = ks*32 + koff;
    u32x8 ld = *(const u32x8*)(eo32 + arow*512 + kb);
    bf16x8 ah, al;
    #pragma unroll
    for (int j=0;j<8;j++){ ah[j] = (short)(ld[j] & 0xFFFFu); al[j] = (short)(ld[j] >> 16); }
    #pragma unroll
    for (int nf=0; nf<4; nf++){
      bf16x8 bh = *(const bf16x8*)(Wet_hi + wro[nf] + kb);
      bf16x8 bl = *(const bf16x8*)(Wet_lo + wro[nf] + kb);
      acc[nf] = __builtin_amdgcn_mfma_f32_16x16x32_bf16(ah, bh, acc[nf], 0,0,0);
      acc[nf] = __builtin_amdgcn_mfma_f32_16x16x32_bf16(ah, bl, acc[nf], 0,0,0);
      acc[nf] = __builtin_amdgcn_mfma_f32_16x16x32_bf16(al, bh, acc[nf], 0,0,0);
    }
  }
  #pragma unroll
  for (int nf=0; nf<4; nf++)
    #pragma unroll
    for (int r=0; r<4; r++){
      size_t orow = (size_t)blockIdx.x*64 + wave*16 + kblk*4 + r;
      ep[orow*64 + nf*16 + lrow] = acc[nf][r];
    }
}

// ---- generic fp32 SGEMM for the two small init GEMMs ----
__global__ __launch_bounds__(256) void sgemm_bias(
    const float* __restrict__ A, const float* __restrict__ W,
    const float* __restrict__ bias, float* __restrict__ C,
    int M, int N, int K, int act)
{
  __shared__ float As[64][17];
  __shared__ float Ws[16][64];
  int tid = threadIdx.x;
  int tr = tid >> 4, tc = tid & 15;
  int row0 = blockIdx.y * 64, col0 = blockIdx.x * 64;
  float acc[4][4] = {};
  for (int k0 = 0; k0 < K; k0 += 16) {
    for (int i = tid; i < 64*16; i += 256) {
      int r = i >> 4, kk = i & 15;
      int gr = row0 + r, gk = k0 + kk;
      As[r][kk] = (gr < M && gk < K) ? A[(size_t)gr*K + gk] : 0.f;
    }
    for (int i = tid; i < 16*64; i += 256) {
      int r = i >> 6, c = i & 63;
      int gk = k0 + r, gc = col0 + c;
      Ws[r][c] = (gk < K && gc < N) ? W[(size_t)gk*N + gc] : 0.f;
    }
    __syncthreads();
    #pragma unroll
    for (int kk=0;kk<16;kk++){
      float a0 = As[tr*4+0][kk], a1 = As[tr*4+1][kk];
      float a2v = As[tr*4+2][kk], a3 = As[tr*4+3][kk];
      float4 b4 = *(const float4*)&Ws[kk][tc*4];
      acc[0][0]+=a0*b4.x; acc[0][1]+=a0*b4.y; acc[0][2]+=a0*b4.z; acc[0][3]+=a0*b4.w;
      acc[1][0]+=a1*b4.x; acc[1][1]+=a1*b4.y; acc[1][2]+=a1*b4.z; acc[1][3]+=a1*b4.w;
      acc[2][0]+=a2v*b4.x; acc[2][1]+=a2v*b4.y; acc[2][2]+=a2v*b4.z; acc[2][3]+=a2v*b4.w;
      acc[3][0]+=a3*b4.x; acc[3][1]+=a3*b4.y; acc[3][2]+=a3*b4.z; acc[3][3]+=a3*b4.w;
    }
    __syncthreads();
  }
  #pragma unroll
  for (int i=0;i<4;i++){
    int r = row0 + tr*4 + i; if (r >= M) continue;
    #pragma unroll
    for (int j=0;j<4;j++){
      int c = col0 + tc*4 + j; if (c >= N) continue;
      float vv = acc[i][j] + (bias ? bias[c] : 0.f);
      if (act == 1) vv = tanhf(vv);
      C[(size_t)r*N + c] = vv;
    }
  }
}

// ---- attention step ----
__global__ __launch_bounds__(256) void attn_step(
    const u32* __restrict__ eo32, const float* __restrict__ ep,
    const float* __restrict__ Wd, const float* __restrict__ v,
    const float* __restrict__ Wo, const float* __restrict__ bo,
    const float* __restrict__ h_dec, u32* __restrict__ Ad32,
    float* __restrict__ py, float* __restrict__ out, int s)
{
  __shared__ float sh_h[256], sh_hwd[64], sh_v[64], sh_sc[256], sh_w[256];
  __shared__ float red4[4][64];
  __shared__ float sh_red[4], sh_red2[4];
  int b = blockIdx.x, tid = threadIdx.x;
  float hv = h_dec[b*H_ + tid];
  sh_h[tid] = hv;
  if (tid < 64) sh_v[tid] = v[tid];
  __syncthreads();
  if (s > 0) {
    float p = hv * Wo[tid];
    p = wred_sum(p);
    if ((tid & 63) == 0) sh_red[tid>>6] = p;
    __syncthreads();
    if (tid == 0) {
      float y = sh_red[0]+sh_red[1]+sh_red[2]+sh_red[3] + bo[0];
      out[b*HOR_ + (s-1)] = y;
      py[b] = y;
    }
  }
  {   // hWd with all 256 threads
    int a = tid & 63, q = tid >> 6;
    float ssum = 0.f;
    for (int j=q*64; j<q*64+64; j++) ssum += sh_h[j]*Wd[(size_t)j*A_ + a];
    red4[q][a] = ssum;
    __syncthreads();
    if (tid < 64) sh_hwd[tid] = red4[0][tid]+red4[1][tid]+red4[2][tid]+red4[3][tid];
  }
  __syncthreads();
  int aa = tid & 3;
  #pragma unroll
  for (int p=0;p<4;p++){
    int t = p*64 + (tid>>2);
    const float4* ep4 = (const float4*)(ep + ((size_t)(b*T_+t))*A_ + aa*16);
    float partial = 0.f;
    #pragma unroll
    for (int q=0;q<4;q++){
      float4 e4 = ep4[q];
      int a0 = aa*16 + q*4;
      partial += tanhf(e4.x + sh_hwd[a0+0]) * sh_v[a0+0];
      partial += tanhf(e4.y + sh_hwd[a0+1]) * sh_v[a0+1];
      partial += tanhf(e4.z + sh_hwd[a0+2]) * sh_v[a0+2];
      partial += tanhf(e4.w + sh_hwd[a0+3]) * sh_v[a0+3];
    }
    partial += __shfl_xor(partial, 1);
    partial += __shfl_xor(partial, 2);
    if (aa == 0) sh_sc[t] = partial;
  }
  __syncthreads();
  float sc = sh_sc[tid];
  float m = wred_max(sc);
  if ((tid&63)==0) sh_red[tid>>6] = m;
  __syncthreads();
  m = fmaxf(fmaxf(sh_red[0],sh_red[1]), fmaxf(sh_red[2],sh_red[3]));
  float e = expf(sc - m);
  float su = wred_sum(e);
  if ((tid&63)==0) sh_red2[tid>>6] = su;
  __syncthreads();
  su = (sh_red2[0]+sh_red2[1])+(sh_red2[2]+sh_red2[3]);
  sh_w[tid] = e / su;
  __syncthreads();
  float acc0=0.f, acc1=0.f;
  const u32* eo = eo32 + (size_t)b*T_*512;
  for (int t=0;t<T_;t++){
    float w = sh_w[t];
    acc0 += w * unpack2f(eo[t*512 + tid]);
    acc1 += w * unpack2f(eo[t*512 + 256 + tid]);
  }
  Ad32[(size_t)b*768 + tid]       = packsplit(acc0);
  Ad32[(size_t)b*768 + 256 + tid] = packsplit(acc1);
}

__global__ __launch_bounds__(256) void final_y(const float* __restrict__ h_dec,
    const float* __restrict__ Wo, const float* __restrict__ bo, float* __restrict__ out){
  __shared__ float sh[4];
  int b = blockIdx.x, tid = threadIdx.x;
  float p = h_dec[b*H_+tid]*Wo[tid];
  p = wred_sum(p);
  if ((tid&63)==0) sh[tid>>6]=p;
  __syncthreads();
  if (tid==0) out[b*HOR_ + HOR_-1] = sh[0]+sh[1]+sh[2]+sh[3] + bo[0];
}

__global__ __launch_bounds__(256) void enc_mean_k(const u32* __restrict__ eo32,
                                                  float* __restrict__ em){
  int b = blockIdx.x, tid = threadIdx.x;
  const u32* p = eo32 + (size_t)b*T_*512;
  float s0=0.f, s1=0.f;
  for (int t=0;t<T_;t++){
    s0 += unpack2f(p[t*512+tid]);
    s1 += unpack2f(p[t*512+256+tid]);
  }
  em[(size_t)b*512 + tid]       = s0*(1.f/T_);
  em[(size_t)b*512 + 256 + tid] = s1*(1.f/T_);
}

__global__ void pack_hd(const float* __restrict__ hd, u32* __restrict__ Ad32){
  int i = blockIdx.x*256 + threadIdx.x;
  int b = i >> 8, u = i & 255;
  Ad32[(size_t)b*768 + 512 + u] = packsplit(hd[i]);
}

__global__ void py_init(const float* __restrict__ x, float* __restrict__ py){
  int b = blockIdx.x*256 + threadIdx.x;
  if (b < B_)
    py[b] = (x[(size_t)b*T_*F_ + 255*F_ + 0] +
             x[(size_t)b*T_*F_ + 255*F_ + 2]) * 0.5f;
}

extern "C" void kernel_launch(void* const* d_in, const int* in_sizes, int n_in,
                              void* d_out, int out_size, void* d_ws, size_t ws_size,
                              hipStream_t stream)
{
  const float* x    = (const float*)d_in[0];
  const float* W_sp = (const float*)d_in[1];
  const float* b_sp = (const float*)d_in[2];
  const float* Wx_ef= (const float*)d_in[3];
  const float* Wh_ef= (const float*)d_in[4];
  const float* b_ef = (const float*)d_in[5];
  const float* Wx_eb= (const float*)d_in[6];
  const float* Wh_eb= (const float*)d_in[7];
  const float* b_eb = (const float*)d_in[8];
  const float* We   = (const float*)d_in[9];
  const float* Wd   = (const float*)d_in[10];
  const float* v    = (const float*)d_in[11];
  const float* Wx_d = (const float*)d_in[12];
  const float* Wh_d = (const float*)d_in[13];
  const float* b_d  = (const float*)d_in[14];
  const float* W_ih = (const float*)d_in[15];
  const float* b_ih = (const float*)d_in[16];
  const float* W_ic = (const float*)d_in[17];
  const float* b_ic = (const float*)d_in[18];
  const float* Wo   = (const float*)d_in[19];
  const float* bo   = (const float*)d_in[20];
  float* out = (float*)d_out;

  char* base = (char*)d_ws;
  auto alloc = [&](size_t bytes)->char*{
    char* p = base; base += (bytes + 255) & ~(size_t)255; return p;
  };
  u16* Wenc_hi = (u16*)alloc((size_t)2*1024*448*2);
  u16* Wenc_lo = (u16*)alloc((size_t)2*1024*448*2);
  u16* Wdec_hi = (u16*)alloc((size_t)1024*768*2);
  u16* Wdec_lo = (u16*)alloc((size_t)1024*768*2);
  u16* Wet_hi  = (u16*)alloc((size_t)64*512*2);
  u16* Wet_lo  = (u16*)alloc((size_t)64*512*2);
  u16* hsp_hi  = (u16*)alloc((size_t)T_*B_*DSP_*2);
  u16* hsp_lo  = (u16*)alloc((size_t)T_*B_*DSP_*2);
  u16* h_hi    = (u16*)alloc((size_t)2*2*B_*H_*2);   // [parity][dir][b][u]
  u16* h_lo    = (u16*)alloc((size_t)2*2*B_*H_*2);
  float* c_enc = (float*)alloc((size_t)2*B_*H_*4);
  u32* eo32    = (u32*)alloc((size_t)B_*T_*512*4);
  float* em    = (float*)alloc((size_t)B_*512*4);
  float* ep    = (float*)alloc((size_t)B_*T_*64*4);
  float* hd    = (float*)alloc((size_t)B_*H_*4);
  float* cd    = (float*)alloc((size_t)B_*H_*4);
  u32* Ad32    = (u32*)alloc((size_t)B_*768*4);
  float* pyb   = (float*)alloc((size_t)B_*4);
  if ((size_t)(base - (char*)d_ws) > ws_size) return;

  // one-time weight conversions
  conv_w<<<dim3(1792),256,0,stream>>>(Wx_ef, Wh_ef, Wenc_hi, Wenc_lo, DSP_, 448, 1024);
  conv_w<<<dim3(1792),256,0,stream>>>(Wx_eb, Wh_eb, Wenc_hi+458752, Wenc_lo+458752, DSP_, 448, 1024);
  conv_w<<<dim3(3072),256,0,stream>>>(Wx_d+1024, Wh_d, Wdec_hi, Wdec_lo, 512, 768, 1024);
  conv_w<<<dim3(128),256,0,stream>>>(We, We, Wet_hi, Wet_lo, 512, 512, 64);

  spatial_proj<<<dim3(256),256,0,stream>>>(x, W_sp, b_sp, hsp_hi, hsp_lo);

  hipMemsetAsync(h_hi, 0, (size_t)2*2*B_*H_*2, stream);
  hipMemsetAsync(h_lo, 0, (size_t)2*2*B_*H_*2, stream);
  hipMemsetAsync(c_enc, 0, (size_t)2*B_*H_*4, stream);

  // encoder scan
  for (int s=0; s<T_; s++){
    int p = s & 1;
    enc_step_mfma<<<dim3(16,2),256,0,stream>>>(
        hsp_hi, hsp_lo, Wenc_hi, Wenc_lo, b_ef, b_eb,
        h_hi + (size_t)p*131072, h_lo + (size_t)p*131072,
        h_hi + (size_t)(p^1)*131072, h_lo + (size_t)(p^1)*131072,
        c_enc, eo32, s);
  }

  enc_mean_k<<<dim3(256),256,0,stream>>>(eo32, em);
  sgemm_bias<<<dim3(4,4),256,0,stream>>>(em, W_ih, b_ih, hd, B_, H_, 2*H_, 1);
  sgemm_bias<<<dim3(4,4),256,0,stream>>>(em, W_ic, b_ic, cd, B_, H_, 2*H_, 1);
  pack_hd<<<dim3(256),256,0,stream>>>(hd, Ad32);
  gemm_ep<<<dim3(1024),256,0,stream>>>(eo32, Wet_hi, Wet_lo, ep);
  py_init<<<dim3(1),256,0,stream>>>(x, pyb);

  // decoder
  for (int s=0; s<HOR_; s++){
    attn_step<<<dim3(256),256,0,stream>>>(eo32, ep, Wd, v, Wo, bo, hd, Ad32, pyb, out, s);
    dec_step_mfma<<<dim3(16),256,0,stream>>>(Ad32, Wdec_hi, Wdec_lo, b_d, Wx_d, pyb, cd, hd, Ad32);
  }
  final_y<<<dim3(256),256,0,stream>>>(hd, Wo, bo, out);
}

// Round 3
// 8278.733 us; speedup vs baseline: 1.8524x; 1.8524x over previous
//
#include <hip/hip_runtime.h>
#include <cmath>

#define B_ 256
#define T_ 256
#define F_ 40
#define H_ 256
#define A_ 64
#define HOR_ 60
#define DSP_ 192
#define ENC_NBLK 128
#define WSTR 456   // LDS weight row stride in u16 (448 + pad): 912B row, 16B-aligned, bank-balanced

typedef unsigned short u16;
typedef unsigned int u32;
typedef __attribute__((ext_vector_type(8))) short bf16x8;
typedef __attribute__((ext_vector_type(4))) float f32x4;
typedef __attribute__((ext_vector_type(8))) u32 u32x8;

__device__ __forceinline__ float sigm(float x){ return 1.f/(1.f+expf(-x)); }

__device__ __forceinline__ u16 f2bf(float x){
  u32 u = __float_as_uint(x);
  u32 r = (u + 0x7FFFu + ((u>>16)&1u)) >> 16;
  return (u16)r;
}
__device__ __forceinline__ float bf2f(u16 h){ return __uint_as_float(((u32)h)<<16); }
__device__ __forceinline__ u32 packsplit(float x){
  u16 hi = f2bf(x);
  u16 lo = f2bf(x - bf2f(hi));
  return (u32)hi | ((u32)lo<<16);
}
__device__ __forceinline__ float unpack2f(u32 v){
  return __uint_as_float(v<<16) + __uint_as_float(v & 0xFFFF0000u);
}

__device__ __forceinline__ float wred_sum(float v){
  #pragma unroll
  for (int o=32;o>0;o>>=1) v += __shfl_xor(v,o);
  return v;
}
__device__ __forceinline__ float wred_max(float v){
  #pragma unroll
  for (int o=32;o>0;o>>=1) v = fmaxf(v,__shfl_xor(v,o));
  return v;
}

// ---- weight conversion: dst[n][k] (hi/lo bf16) = src[k][n], src = [Wx ; Wh] ----
__global__ void conv_w(const float* __restrict__ Wx, const float* __restrict__ Wh,
                       u16* __restrict__ hi, u16* __restrict__ lo,
                       int KX, int Ktot, int N){
  int idx = blockIdx.x*256 + threadIdx.x;
  if (idx >= N*Ktot) return;
  int n = idx / Ktot, k = idx - n*Ktot;
  float w = (k < KX) ? Wx[(size_t)k*N + n] : Wh[(size_t)(k-KX)*N + n];
  u16 h = f2bf(w);
  hi[idx] = h;
  lo[idx] = f2bf(w - bf2f(h));
}

// ---- spatial projection: hsp32[t][b][192] packed = x[b][t][:40] @ W_sp + b_sp ----
__global__ __launch_bounds__(192) void spatial_proj(
    const float* __restrict__ x, const float* __restrict__ W, const float* __restrict__ bsp,
    u32* __restrict__ hsp32){
  __shared__ float Ws[40][192];
  __shared__ float xr[40];
  int t = blockIdx.x, tid = threadIdx.x;
  for (int i = tid; i < 40*192; i += 192){ int k = i/192, c = i-k*192; Ws[k][c] = W[i]; }
  float bb = bsp[tid];
  __syncthreads();
  for (int b=0; b<B_; b++){
    if (tid < 40) xr[tid] = x[((size_t)b*T_ + t)*F_ + tid];
    __syncthreads();
    float acc = bb;
    #pragma unroll
    for (int k=0;k<40;k++) acc += xr[k]*Ws[k][tid];
    hsp32[((size_t)t*B_ + b)*DSP_ + tid] = packsplit(acc);
    __syncthreads();
  }
}

// ---- persistent bidirectional encoder scan: one kernel, 256 steps, LDS-resident weights ----
// grid 128 = [dir(2)][mtile(4)][ntile(16)], block 256 (4 waves), LDS ~114KB
__global__ __launch_bounds__(256) void enc_scan(
    const u32* __restrict__ hsp32,
    const u16* __restrict__ W_hi, const u16* __restrict__ W_lo,
    const float* __restrict__ b_ef, const float* __restrict__ b_eb,
    u32* __restrict__ hbuf, u32* __restrict__ eo32, int* __restrict__ bar)
{
  extern __shared__ u16 smem[];
  u16* Whi = smem;                    // [4 gates][16 units][WSTR]
  u16* Wlo = smem + 4*16*WSTR;
  const int bid = blockIdx.x;
  const int dir = bid >> 6;
  const int rem = bid & 63;
  const int u0  = (rem & 15) * 16;
  const int m0  = (rem >> 4) * 64;
  const int tid = threadIdx.x;
  const int wave = tid >> 6, lane = tid & 63;
  const int lrow = lane & 15, kblk = lane >> 4;
  const int koff = kblk * 8;
  {
    const size_t wbase = ((size_t)dir*1024 + u0) * 448;
    for (int idx = tid; idx < 4*16*448; idx += 256){
      int g = idx / (16*448);
      int r = idx - g*(16*448);
      int j = r / 448;
      int k = r - j*448;
      size_t go = wbase + ((size_t)g*256 + j)*448 + k;
      Whi[(g*16 + j)*WSTR + k] = W_hi[go];
      Wlo[(g*16 + j)*WSTR + k] = W_lo[go];
    }
  }
  const float* bias = dir ? b_eb : b_ef;
  float bg4[4];
  #pragma unroll
  for (int g=0; g<4; g++) bg4[g] = bias[g*H_ + u0 + lrow];
  __syncthreads();

  const int mrow = m0 + wave*16;
  const int arow = mrow + lrow;
  u32* hP0 = hbuf + (size_t)dir*(B_*H_);
  u32* hP1 = hbuf + (size_t)(2+dir)*(B_*H_);
  float c_reg[4] = {0.f,0.f,0.f,0.f};

  for (int s=0; s<T_; s++){
    const int t = dir ? (T_-1-s) : s;
    const u32* hin = (s & 1) ? hP1 : hP0;
    u32* hout = (s & 1) ? hP0 : hP1;
    f32x4 acc[4] = {};
    // x part: k 0..191
    const u32* abase = hsp32 + ((size_t)t*B_ + arow)*DSP_;
    #pragma unroll
    for (int ks=0; ks<6; ks++){
      int kb = ks*32 + koff;
      u32x8 la = *(const u32x8*)(abase + kb);
      bf16x8 ah, al;
      #pragma unroll
      for (int j=0;j<8;j++){ ah[j]=(short)(la[j]&0xFFFFu); al[j]=(short)(la[j]>>16); }
      #pragma unroll
      for (int g=0; g<4; g++){
        bf16x8 bh = *(const bf16x8*)(Whi + (g*16+lrow)*WSTR + kb);
        bf16x8 bl = *(const bf16x8*)(Wlo + (g*16+lrow)*WSTR + kb);
        acc[g] = __builtin_amdgcn_mfma_f32_16x16x32_bf16(ah, bh, acc[g], 0,0,0);
        acc[g] = __builtin_amdgcn_mfma_f32_16x16x32_bf16(ah, bl, acc[g], 0,0,0);
        acc[g] = __builtin_amdgcn_mfma_f32_16x16x32_bf16(al, bh, acc[g], 0,0,0);
      }
    }
    // h part: k 192..447
    const u32* hbase = hin + (size_t)arow*H_;
    #pragma unroll
    for (int ks=0; ks<8; ks++){
      int kb = ks*32 + koff;
      u32x8 la = *(const u32x8*)(hbase + kb);
      bf16x8 ah, al;
      #pragma unroll
      for (int j=0;j<8;j++){ ah[j]=(short)(la[j]&0xFFFFu); al[j]=(short)(la[j]>>16); }
      #pragma unroll
      for (int g=0; g<4; g++){
        bf16x8 bh = *(const bf16x8*)(Whi + (g*16+lrow)*WSTR + 192 + kb);
        bf16x8 bl = *(const bf16x8*)(Wlo + (g*16+lrow)*WSTR + 192 + kb);
        acc[g] = __builtin_amdgcn_mfma_f32_16x16x32_bf16(ah, bh, acc[g], 0,0,0);
        acc[g] = __builtin_amdgcn_mfma_f32_16x16x32_bf16(ah, bl, acc[g], 0,0,0);
        acc[g] = __builtin_amdgcn_mfma_f32_16x16x32_bf16(al, bh, acc[g], 0,0,0);
      }
    }
    // cell (c in registers), h/eo writes
    #pragma unroll
    for (int r=0; r<4; r++){
      int brow = mrow + kblk*4 + r;
      float gi = acc[0][r] + bg4[0];
      float gf = acc[1][r] + bg4[1];
      float gg = acc[2][r] + bg4[2];
      float go = acc[3][r] + bg4[3];
      float cn = sigm(gf)*c_reg[r] + sigm(gi)*tanhf(gg);
      float hn = sigm(go)*tanhf(cn);
      c_reg[r] = cn;
      u32 hp = packsplit(hn);
      hout[(size_t)brow*H_ + u0 + lrow] = hp;
      eo32[((size_t)brow*T_ + t)*512 + dir*H_ + u0 + lrow] = hp;
    }
    if (s == T_-1) break;
    __syncthreads();
    if (tid == 0){
      __hip_atomic_fetch_add(&bar[s], 1, __ATOMIC_RELEASE, __HIP_MEMORY_SCOPE_AGENT);
      while (__hip_atomic_load(&bar[s], __ATOMIC_ACQUIRE, __HIP_MEMORY_SCOPE_AGENT) < ENC_NBLK) {}
    }
    __syncthreads();
  }
}

// ---- decoder LSTM step: grid (16 ntiles, 8 mtiles) x 128 threads ----
__global__ __launch_bounds__(128) void dec_step_mfma(
    const u32* __restrict__ Ad32,
    const u16* __restrict__ W_hi, const u16* __restrict__ W_lo,
    const float* __restrict__ b_d, const float* __restrict__ Wx_d,
    const float* __restrict__ py,
    float* __restrict__ c_dec, float* __restrict__ h_dec,
    u32* __restrict__ AdW)
{
  const int u0 = blockIdx.x * 16;
  const int tid = threadIdx.x;
  const int wave = tid >> 6, lane = tid & 63;
  const int lrow = lane & 15, kblk = lane >> 4;
  const int u = u0 + lrow;
  const int mbase = blockIdx.y * 32 + wave * 16;
  const int koff = kblk * 8;
  size_t wro[4];
  #pragma unroll
  for (int g=0; g<4; g++) wro[g] = (size_t)(g*H_ + u) * 768;
  f32x4 acc[4] = {};
  const u32* abase = Ad32 + (size_t)(mbase + lrow)*768;
  for (int ks=0; ks<24; ks++){
    int kb = ks*32 + koff;
    u32x8 ld = *(const u32x8*)(abase + kb);
    bf16x8 ah, al;
    #pragma unroll
    for (int j=0;j<8;j++){ ah[j] = (short)(ld[j] & 0xFFFFu); al[j] = (short)(ld[j] >> 16); }
    #pragma unroll
    for (int g=0; g<4; g++){
      bf16x8 bh = *(const bf16x8*)(W_hi + wro[g] + kb);
      bf16x8 bl = *(const bf16x8*)(W_lo + wro[g] + kb);
      acc[g] = __builtin_amdgcn_mfma_f32_16x16x32_bf16(ah, bh, acc[g], 0,0,0);
      acc[g] = __builtin_amdgcn_mfma_f32_16x16x32_bf16(ah, bl, acc[g], 0,0,0);
      acc[g] = __builtin_amdgcn_mfma_f32_16x16x32_bf16(al, bh, acc[g], 0,0,0);
    }
  }
  float bg4[4], w0g[4];
  #pragma unroll
  for (int g=0;g<4;g++){ bg4[g] = b_d[g*H_ + u]; w0g[g] = Wx_d[g*H_ + u]; }
  #pragma unroll
  for (int r=0; r<4; r++){
    int b = mbase + kblk*4 + r;
    float pyb = py[b];
    float gi = acc[0][r] + bg4[0] + pyb*w0g[0];
    float gf = acc[1][r] + bg4[1] + pyb*w0g[1];
    float gg = acc[2][r] + bg4[2] + pyb*w0g[2];
    float go = acc[3][r] + bg4[3] + pyb*w0g[3];
    size_t ci = (size_t)b*H_ + u;
    float cn = sigm(gf)*c_dec[ci] + sigm(gi)*tanhf(gg);
    float hn = sigm(go)*tanhf(cn);
    c_dec[ci] = cn;
    h_dec[ci] = hn;
    AdW[(size_t)b*768 + 512 + u] = packsplit(hn);
  }
}

// ---- enc_proj: ep[bt][64] = eo @ We ----
__global__ __launch_bounds__(256) void gemm_ep(
    const u32* __restrict__ eo32, const u16* __restrict__ Wet_hi, const u16* __restrict__ Wet_lo,
    float* __restrict__ ep)
{
  const int tid = threadIdx.x, wave = tid>>6, lane = tid&63;
  const int lrow = lane&15, kblk = lane>>4, koff = kblk*8;
  const size_t arow = (size_t)blockIdx.x*64 + wave*16 + lrow;
  f32x4 acc[4] = {};
  size_t wro[4];
  #pragma unroll
  for (int nf=0; nf<4; nf++) wro[nf] = (size_t)(nf*16 + lrow)*512;
  for (int ks=0; ks<16; ks++){
    int kb = ks*32 + koff;
    u32x8 ld = *(const u32x8*)(eo32 + arow*512 + kb);
    bf16x8 ah, al;
    #pragma unroll
    for (int j=0;j<8;j++){ ah[j] = (short)(ld[j] & 0xFFFFu); al[j] = (short)(ld[j] >> 16); }
    #pragma unroll
    for (int nf=0; nf<4; nf++){
      bf16x8 bh = *(const bf16x8*)(Wet_hi + wro[nf] + kb);
      bf16x8 bl = *(const bf16x8*)(Wet_lo + wro[nf] + kb);
      acc[nf] = __builtin_amdgcn_mfma_f32_16x16x32_bf16(ah, bh, acc[nf], 0,0,0);
      acc[nf] = __builtin_amdgcn_mfma_f32_16x16x32_bf16(ah, bl, acc[nf], 0,0,0);
      acc[nf] = __builtin_amdgcn_mfma_f32_16x16x32_bf16(al, bh, acc[nf], 0,0,0);
    }
  }
  #pragma unroll
  for (int nf=0; nf<4; nf++)
    #pragma unroll
    for (int r=0; r<4; r++){
      size_t orow = (size_t)blockIdx.x*64 + wave*16 + kblk*4 + r;
      ep[orow*64 + nf*16 + lrow] = acc[nf][r];
    }
}

// ---- generic fp32 SGEMM for small init GEMMs ----
__global__ __launch_bounds__(256) void sgemm_bias(
    const float* __restrict__ A, const float* __restrict__ W,
    const float* __restrict__ bias, float* __restrict__ C,
    int M, int N, int K, int act)
{
  __shared__ float As[64][17];
  __shared__ float Ws[16][64];
  int tid = threadIdx.x;
  int tr = tid >> 4, tc = tid & 15;
  int row0 = blockIdx.y * 64, col0 = blockIdx.x * 64;
  float acc[4][4] = {};
  for (int k0 = 0; k0 < K; k0 += 16) {
    for (int i = tid; i < 64*16; i += 256) {
      int r = i >> 4, kk = i & 15;
      int gr = row0 + r, gk = k0 + kk;
      As[r][kk] = (gr < M && gk < K) ? A[(size_t)gr*K + gk] : 0.f;
    }
    for (int i = tid; i < 16*64; i += 256) {
      int r = i >> 6, c = i & 63;
      int gk = k0 + r, gc = col0 + c;
      Ws[r][c] = (gk < K && gc < N) ? W[(size_t)gk*N + gc] : 0.f;
    }
    __syncthreads();
    #pragma unroll
    for (int kk=0;kk<16;kk++){
      float a0 = As[tr*4+0][kk], a1 = As[tr*4+1][kk];
      float a2v = As[tr*4+2][kk], a3 = As[tr*4+3][kk];
      float4 b4 = *(const float4*)&Ws[kk][tc*4];
      acc[0][0]+=a0*b4.x; acc[0][1]+=a0*b4.y; acc[0][2]+=a0*b4.z; acc[0][3]+=a0*b4.w;
      acc[1][0]+=a1*b4.x; acc[1][1]+=a1*b4.y; acc[1][2]+=a1*b4.z; acc[1][3]+=a1*b4.w;
      acc[2][0]+=a2v*b4.x; acc[2][1]+=a2v*b4.y; acc[2][2]+=a2v*b4.z; acc[2][3]+=a2v*b4.w;
      acc[3][0]+=a3*b4.x; acc[3][1]+=a3*b4.y; acc[3][2]+=a3*b4.z; acc[3][3]+=a3*b4.w;
    }
    __syncthreads();
  }
  #pragma unroll
  for (int i=0;i<4;i++){
    int r = row0 + tr*4 + i; if (r >= M) continue;
    #pragma unroll
    for (int j=0;j<4;j++){
      int c = col0 + tc*4 + j; if (c >= N) continue;
      float vv = acc[i][j] + (bias ? bias[c] : 0.f);
      if (act == 1) vv = tanhf(vv);
      C[(size_t)r*N + c] = vv;
    }
  }
}

// ---- attention step ----
__global__ __launch_bounds__(256) void attn_step(
    const u32* __restrict__ eo32, const float* __restrict__ ep,
    const float* __restrict__ Wd, const float* __restrict__ v,
    const float* __restrict__ Wo, const float* __restrict__ bo,
    const float* __restrict__ h_dec, u32* __restrict__ Ad32,
    float* __restrict__ py, float* __restrict__ out, int s)
{
  __shared__ float sh_h[256], sh_hwd[64], sh_v[64], sh_sc[256], sh_w[256];
  __shared__ float red4[4][64];
  __shared__ float sh_red[4], sh_red2[4];
  int b = blockIdx.x, tid = threadIdx.x;
  float hv = h_dec[b*H_ + tid];
  sh_h[tid] = hv;
  if (tid < 64) sh_v[tid] = v[tid];
  __syncthreads();
  if (s > 0) {
    float p = hv * Wo[tid];
    p = wred_sum(p);
    if ((tid & 63) == 0) sh_red[tid>>6] = p;
    __syncthreads();
    if (tid == 0) {
      float y = sh_red[0]+sh_red[1]+sh_red[2]+sh_red[3] + bo[0];
      out[b*HOR_ + (s-1)] = y;
      py[b] = y;
    }
  }
  {
    int a = tid & 63, q = tid >> 6;
    float ssum = 0.f;
    for (int j=q*64; j<q*64+64; j++) ssum += sh_h[j]*Wd[(size_t)j*A_ + a];
    red4[q][a] = ssum;
    __syncthreads();
    if (tid < 64) sh_hwd[tid] = red4[0][tid]+red4[1][tid]+red4[2][tid]+red4[3][tid];
  }
  __syncthreads();
  int aa = tid & 3;
  #pragma unroll
  for (int p=0;p<4;p++){
    int t = p*64 + (tid>>2);
    const float4* ep4 = (const float4*)(ep + ((size_t)(b*T_+t))*A_ + aa*16);
    float partial = 0.f;
    #pragma unroll
    for (int q=0;q<4;q++){
      float4 e4 = ep4[q];
      int a0 = aa*16 + q*4;
      partial += tanhf(e4.x + sh_hwd[a0+0]) * sh_v[a0+0];
      partial += tanhf(e4.y + sh_hwd[a0+1]) * sh_v[a0+1];
      partial += tanhf(e4.z + sh_hwd[a0+2]) * sh_v[a0+2];
      partial += tanhf(e4.w + sh_hwd[a0+3]) * sh_v[a0+3];
    }
    partial += __shfl_xor(partial, 1);
    partial += __shfl_xor(partial, 2);
    if (aa == 0) sh_sc[t] = partial;
  }
  __syncthreads();
  float sc = sh_sc[tid];
  float m = wred_max(sc);
  if ((tid&63)==0) sh_red[tid>>6] = m;
  __syncthreads();
  m = fmaxf(fmaxf(sh_red[0],sh_red[1]), fmaxf(sh_red[2],sh_red[3]));
  float e = expf(sc - m);
  float su = wred_sum(e);
  if ((tid&63)==0) sh_red2[tid>>6] = su;
  __syncthreads();
  su = (sh_red2[0]+sh_red2[1])+(sh_red2[2]+sh_red2[3]);
  sh_w[tid] = e / su;
  __syncthreads();
  float acc0=0.f, acc1=0.f;
  const u32* eo = eo32 + (size_t)b*T_*512;
  for (int t=0;t<T_;t++){
    float w = sh_w[t];
    acc0 += w * unpack2f(eo[t*512 + tid]);
    acc1 += w * unpack2f(eo[t*512 + 256 + tid]);
  }
  Ad32[(size_t)b*768 + tid]       = packsplit(acc0);
  Ad32[(size_t)b*768 + 256 + tid] = packsplit(acc1);
}

__global__ __launch_bounds__(256) void final_y(const float* __restrict__ h_dec,
    const float* __restrict__ Wo, const float* __restrict__ bo, float* __restrict__ out){
  __shared__ float sh[4];
  int b = blockIdx.x, tid = threadIdx.x;
  float p = h_dec[b*H_+tid]*Wo[tid];
  p = wred_sum(p);
  if ((tid&63)==0) sh[tid>>6]=p;
  __syncthreads();
  if (tid==0) out[b*HOR_ + HOR_-1] = sh[0]+sh[1]+sh[2]+sh[3] + bo[0];
}

__global__ __launch_bounds__(256) void enc_mean_k(const u32* __restrict__ eo32,
                                                  float* __restrict__ em){
  int b = blockIdx.x, tid = threadIdx.x;
  const u32* p = eo32 + (size_t)b*T_*512;
  float s0=0.f, s1=0.f;
  for (int t=0;t<T_;t++){
    s0 += unpack2f(p[t*512+tid]);
    s1 += unpack2f(p[t*512+256+tid]);
  }
  em[(size_t)b*512 + tid]       = s0*(1.f/T_);
  em[(size_t)b*512 + 256 + tid] = s1*(1.f/T_);
}

__global__ void pack_hd(const float* __restrict__ hd, u32* __restrict__ Ad32){
  int i = blockIdx.x*256 + threadIdx.x;
  int b = i >> 8, u = i & 255;
  Ad32[(size_t)b*768 + 512 + u] = packsplit(hd[i]);
}

__global__ void py_init(const float* __restrict__ x, float* __restrict__ py){
  int b = blockIdx.x*256 + threadIdx.x;
  if (b < B_)
    py[b] = (x[(size_t)b*T_*F_ + 255*F_ + 0] +
             x[(size_t)b*T_*F_ + 255*F_ + 2]) * 0.5f;
}

extern "C" void kernel_launch(void* const* d_in, const int* in_sizes, int n_in,
                              void* d_out, int out_size, void* d_ws, size_t ws_size,
                              hipStream_t stream)
{
  const float* x    = (const float*)d_in[0];
  const float* W_sp = (const float*)d_in[1];
  const float* b_sp = (const float*)d_in[2];
  const float* Wx_ef= (const float*)d_in[3];
  const float* Wh_ef= (const float*)d_in[4];
  const float* b_ef = (const float*)d_in[5];
  const float* Wx_eb= (const float*)d_in[6];
  const float* Wh_eb= (const float*)d_in[7];
  const float* b_eb = (const float*)d_in[8];
  const float* We   = (const float*)d_in[9];
  const float* Wd   = (const float*)d_in[10];
  const float* v    = (const float*)d_in[11];
  const float* Wx_d = (const float*)d_in[12];
  const float* Wh_d = (const float*)d_in[13];
  const float* b_d  = (const float*)d_in[14];
  const float* W_ih = (const float*)d_in[15];
  const float* b_ih = (const float*)d_in[16];
  const float* W_ic = (const float*)d_in[17];
  const float* b_ic = (const float*)d_in[18];
  const float* Wo   = (const float*)d_in[19];
  const float* bo   = (const float*)d_in[20];
  float* out = (float*)d_out;

  char* base = (char*)d_ws;
  auto alloc = [&](size_t bytes)->char*{
    char* p = base; base += (bytes + 255) & ~(size_t)255; return p;
  };
  u16* Wenc_hi = (u16*)alloc((size_t)2*1024*448*2);
  u16* Wenc_lo = (u16*)alloc((size_t)2*1024*448*2);
  u16* Wdec_hi = (u16*)alloc((size_t)1024*768*2);
  u16* Wdec_lo = (u16*)alloc((size_t)1024*768*2);
  u16* Wet_hi  = (u16*)alloc((size_t)64*512*2);
  u16* Wet_lo  = (u16*)alloc((size_t)64*512*2);
  u32* hsp32   = (u32*)alloc((size_t)T_*B_*DSP_*4);
  u32* hbuf    = (u32*)alloc((size_t)2*2*B_*H_*4);   // [parity][dir][b][u]
  u32* eo32    = (u32*)alloc((size_t)B_*T_*512*4);
  float* em    = (float*)alloc((size_t)B_*512*4);
  float* ep    = (float*)alloc((size_t)B_*T_*64*4);
  float* hd    = (float*)alloc((size_t)B_*H_*4);
  float* cd    = (float*)alloc((size_t)B_*H_*4);
  u32* Ad32    = (u32*)alloc((size_t)B_*768*4);
  float* pyb   = (float*)alloc((size_t)B_*4);
  int* bar     = (int*)alloc((size_t)T_*4);
  if ((size_t)(base - (char*)d_ws) > ws_size) return;

  // one-time weight conversions
  conv_w<<<dim3(1792),256,0,stream>>>(Wx_ef, Wh_ef, Wenc_hi, Wenc_lo, DSP_, 448, 1024);
  conv_w<<<dim3(1792),256,0,stream>>>(Wx_eb, Wh_eb, Wenc_hi+458752, Wenc_lo+458752, DSP_, 448, 1024);
  conv_w<<<dim3(3072),256,0,stream>>>(Wx_d+1024, Wh_d, Wdec_hi, Wdec_lo, 512, 768, 1024);
  conv_w<<<dim3(128),256,0,stream>>>(We, We, Wet_hi, Wet_lo, 512, 512, 64);

  spatial_proj<<<dim3(256),192,0,stream>>>(x, W_sp, b_sp, hsp32);

  hipMemsetAsync(hbuf, 0, (size_t)2*B_*H_*4, stream);      // parity-0 h = 0
  hipMemsetAsync(bar, 0, (size_t)T_*4, stream);            // barrier slots

  // whole encoder scan in ONE persistent kernel
  enc_scan<<<dim3(ENC_NBLK), dim3(256), 2*4*16*WSTR*2, stream>>>(
      hsp32, Wenc_hi, Wenc_lo, b_ef, b_eb, hbuf, eo32, bar);

  enc_mean_k<<<dim3(256),256,0,stream>>>(eo32, em);
  sgemm_bias<<<dim3(4,4),256,0,stream>>>(em, W_ih, b_ih, hd, B_, H_, 2*H_, 1);
  sgemm_bias<<<dim3(4,4),256,0,stream>>>(em, W_ic, b_ic, cd, B_, H_, 2*H_, 1);
  pack_hd<<<dim3(256),256,0,stream>>>(hd, Ad32);
  gemm_ep<<<dim3(1024),256,0,stream>>>(eo32, Wet_hi, Wet_lo, ep);
  py_init<<<dim3(1),256,0,stream>>>(x, pyb);

  // decoder
  for (int s=0; s<HOR_; s++){
    attn_step<<<dim3(256),256,0,stream>>>(eo32, ep, Wd, v, Wo, bo, hd, Ad32, pyb, out, s);
    dec_step_mfma<<<dim3(16,8),128,0,stream>>>(Ad32, Wdec_hi, Wdec_lo, b_d, Wx_d, pyb, cd, hd, Ad32);
  }
  final_y<<<dim3(256),256,0,stream>>>(hd, Wo, bo, out);
}

// Round 4
// 6543.153 us; speedup vs baseline: 2.3437x; 1.2653x over previous
//
#include <hip/hip_runtime.h>
#include <cmath>

#define B_ 256
#define T_ 256
#define F_ 40
#define H_ 256
#define A_ 64
#define HOR_ 60
#define DSP_ 192
#define ENC_NBLK 128
#define GRP_SZ 16     // blocks per barrier group (one dir x mtile)
#define WSTR 456      // LDS weight row stride in u16 (448 + pad)

typedef unsigned short u16;
typedef unsigned int u32;
typedef __attribute__((ext_vector_type(8))) short bf16x8;
typedef __attribute__((ext_vector_type(4))) float f32x4;
typedef __attribute__((ext_vector_type(8))) u32 u32x8;
typedef __attribute__((ext_vector_type(4))) u32 u32x4;

__device__ __forceinline__ float sigm(float x){ return 1.f/(1.f+expf(-x)); }

__device__ __forceinline__ u16 f2bf(float x){
  u32 u = __float_as_uint(x);
  u32 r = (u + 0x7FFFu + ((u>>16)&1u)) >> 16;
  return (u16)r;
}
__device__ __forceinline__ float bf2f(u16 h){ return __uint_as_float(((u32)h)<<16); }
__device__ __forceinline__ u32 packsplit(float x){
  u16 hi = f2bf(x);
  u16 lo = f2bf(x - bf2f(hi));
  return (u32)hi | ((u32)lo<<16);
}
__device__ __forceinline__ float unpack2f(u32 v){
  return __uint_as_float(v<<16) + __uint_as_float(v & 0xFFFF0000u);
}

__device__ __forceinline__ float wred_sum(float v){
  #pragma unroll
  for (int o=32;o>0;o>>=1) v += __shfl_xor(v,o);
  return v;
}
__device__ __forceinline__ float wred_max(float v){
  #pragma unroll
  for (int o=32;o>0;o>>=1) v = fmaxf(v,__shfl_xor(v,o));
  return v;
}

// ---- weight conversion: dst[n][k] (hi/lo bf16) = src[k][n], src = [Wx ; Wh] ----
__global__ void conv_w(const float* __restrict__ Wx, const float* __restrict__ Wh,
                       u16* __restrict__ hi, u16* __restrict__ lo,
                       int KX, int Ktot, int N){
  int idx = blockIdx.x*256 + threadIdx.x;
  if (idx >= N*Ktot) return;
  int n = idx / Ktot, k = idx - n*Ktot;
  float w = (k < KX) ? Wx[(size_t)k*N + n] : Wh[(size_t)(k-KX)*N + n];
  u16 h = f2bf(w);
  hi[idx] = h;
  lo[idx] = f2bf(w - bf2f(h));
}

// ---- spatial projection: hsp32[t][b][192] packed = x[b][t][:40] @ W_sp + b_sp ----
__global__ __launch_bounds__(192) void spatial_proj(
    const float* __restrict__ x, const float* __restrict__ W, const float* __restrict__ bsp,
    u32* __restrict__ hsp32){
  __shared__ float Ws[40][192];
  __shared__ float xr[40];
  int t = blockIdx.x, tid = threadIdx.x;
  for (int i = tid; i < 40*192; i += 192){ int k = i/192, c = i-k*192; Ws[k][c] = W[i]; }
  float bb = bsp[tid];
  __syncthreads();
  for (int b=0; b<B_; b++){
    if (tid < 40) xr[tid] = x[((size_t)b*T_ + t)*F_ + tid];
    __syncthreads();
    float acc = bb;
    #pragma unroll
    for (int k=0;k<40;k++) acc += xr[k]*Ws[k][tid];
    hsp32[((size_t)t*B_ + b)*DSP_ + tid] = packsplit(acc);
    __syncthreads();
  }
}

// ---- persistent bidirectional encoder scan ----
// grid 128: grp = bid&7 (dir*4+mtile, XCD-aligned), nt = bid>>3 (unit tile)
// per step: x-part MFMAs BEFORE the group barrier (h-independent), h-part after.
__global__ __launch_bounds__(256) void enc_scan(
    const u32* __restrict__ hsp32,
    const u16* __restrict__ W_hi, const u16* __restrict__ W_lo,
    const float* __restrict__ b_ef, const float* __restrict__ b_eb,
    u32* __restrict__ hbuf, u32* __restrict__ eo32, int* __restrict__ bar)
{
  extern __shared__ u16 smem[];
  u16* Whi = smem;                    // [4 gates][16 units][WSTR]
  u16* Wlo = smem + 4*16*WSTR;
  const int bid = blockIdx.x;
  const int grp = bid & 7;            // dir*4 + mtile  (same XCD under round-robin)
  const int nt  = bid >> 3;
  const int dir = grp >> 2;
  const int m0  = (grp & 3) * 64;
  const int u0  = nt * 16;
  const int tid = threadIdx.x;
  const int wave = tid >> 6, lane = tid & 63;
  const int lrow = lane & 15, kblk = lane >> 4;
  const int koff = kblk * 8;
  {
    const size_t wbase = ((size_t)dir*1024 + u0) * 448;
    for (int idx = tid; idx < 4*16*448; idx += 256){
      int g = idx / (16*448);
      int r = idx - g*(16*448);
      int j = r / 448;
      int k = r - j*448;
      size_t go = wbase + ((size_t)g*256 + j)*448 + k;
      Whi[(g*16 + j)*WSTR + k] = W_hi[go];
      Wlo[(g*16 + j)*WSTR + k] = W_lo[go];
    }
  }
  const float* bias = dir ? b_eb : b_ef;
  float bg4[4];
  #pragma unroll
  for (int g=0; g<4; g++) bg4[g] = bias[g*H_ + u0 + lrow];
  __syncthreads();

  const int mrow = m0 + wave*16;
  const int arow = mrow + lrow;
  u32* hP0 = hbuf + (size_t)dir*(B_*H_);
  u32* hP1 = hbuf + (size_t)(2+dir)*(B_*H_);
  int* gbar = bar + grp*T_;
  float c_reg[4] = {0.f,0.f,0.f,0.f};

  for (int s=0; s<T_; s++){
    const int t = dir ? (T_-1-s) : s;
    f32x4 acc[4] = {};
    // ---- x part (k 0..191): independent of h -> before barrier ----
    const u32* abase = hsp32 + ((size_t)t*B_ + arow)*DSP_;
    #pragma unroll
    for (int ks=0; ks<6; ks++){
      int kb = ks*32 + koff;
      u32x8 la = *(const u32x8*)(abase + kb);
      bf16x8 ah, al;
      #pragma unroll
      for (int j=0;j<8;j++){ ah[j]=(short)(la[j]&0xFFFFu); al[j]=(short)(la[j]>>16); }
      #pragma unroll
      for (int g=0; g<4; g++){
        bf16x8 bh = *(const bf16x8*)(Whi + (g*16+lrow)*WSTR + kb);
        bf16x8 bl = *(const bf16x8*)(Wlo + (g*16+lrow)*WSTR + kb);
        acc[g] = __builtin_amdgcn_mfma_f32_16x16x32_bf16(ah, bh, acc[g], 0,0,0);
        acc[g] = __builtin_amdgcn_mfma_f32_16x16x32_bf16(ah, bl, acc[g], 0,0,0);
        acc[g] = __builtin_amdgcn_mfma_f32_16x16x32_bf16(al, bh, acc[g], 0,0,0);
      }
    }
    // ---- wait for group's h(s-1) ----
    if (s > 0){
      if (tid == 0){
        while (__hip_atomic_load(&gbar[s-1], __ATOMIC_ACQUIRE, __HIP_MEMORY_SCOPE_AGENT) < GRP_SZ)
          __builtin_amdgcn_s_sleep(1);
      }
      __syncthreads();
    }
    const u32* hin = (s & 1) ? hP1 : hP0;
    u32* hout      = (s & 1) ? hP0 : hP1;
    // ---- h part (k 192..447) ----
    const u32* hbase = hin + (size_t)arow*H_;
    #pragma unroll
    for (int ks=0; ks<8; ks++){
      int kb = ks*32 + koff;
      u32x8 la = *(const u32x8*)(hbase + kb);
      bf16x8 ah, al;
      #pragma unroll
      for (int j=0;j<8;j++){ ah[j]=(short)(la[j]&0xFFFFu); al[j]=(short)(la[j]>>16); }
      #pragma unroll
      for (int g=0; g<4; g++){
        bf16x8 bh = *(const bf16x8*)(Whi + (g*16+lrow)*WSTR + 192 + kb);
        bf16x8 bl = *(const bf16x8*)(Wlo + (g*16+lrow)*WSTR + 192 + kb);
        acc[g] = __builtin_amdgcn_mfma_f32_16x16x32_bf16(ah, bh, acc[g], 0,0,0);
        acc[g] = __builtin_amdgcn_mfma_f32_16x16x32_bf16(ah, bl, acc[g], 0,0,0);
        acc[g] = __builtin_amdgcn_mfma_f32_16x16x32_bf16(al, bh, acc[g], 0,0,0);
      }
    }
    // ---- cell + writes (h first: it is the critical path) ----
    #pragma unroll
    for (int r=0; r<4; r++){
      int brow = mrow + kblk*4 + r;
      float gi = acc[0][r] + bg4[0];
      float gf = acc[1][r] + bg4[1];
      float gg = acc[2][r] + bg4[2];
      float go = acc[3][r] + bg4[3];
      float cn = sigm(gf)*c_reg[r] + sigm(gi)*tanhf(gg);
      float hn = sigm(go)*tanhf(cn);
      c_reg[r] = cn;
      u32 hp = packsplit(hn);
      hout[(size_t)brow*H_ + u0 + lrow] = hp;
      __builtin_nontemporal_store(hp, &eo32[((size_t)brow*T_ + t)*512 + dir*H_ + u0 + lrow]);
    }
    if (s == T_-1) break;
    __syncthreads();
    if (tid == 0)
      __hip_atomic_fetch_add(&gbar[s], 1, __ATOMIC_RELEASE, __HIP_MEMORY_SCOPE_AGENT);
  }
}

// ---- decoder LSTM step ----
__global__ __launch_bounds__(128) void dec_step_mfma(
    const u32* __restrict__ Ad32,
    const u16* __restrict__ W_hi, const u16* __restrict__ W_lo,
    const float* __restrict__ b_d, const float* __restrict__ Wx_d,
    const float* __restrict__ py,
    float* __restrict__ c_dec, float* __restrict__ h_dec,
    u32* __restrict__ AdW)
{
  const int u0 = blockIdx.x * 16;
  const int tid = threadIdx.x;
  const int wave = tid >> 6, lane = tid & 63;
  const int lrow = lane & 15, kblk = lane >> 4;
  const int u = u0 + lrow;
  const int mbase = blockIdx.y * 32 + wave * 16;
  const int koff = kblk * 8;
  size_t wro[4];
  #pragma unroll
  for (int g=0; g<4; g++) wro[g] = (size_t)(g*H_ + u) * 768;
  f32x4 acc[4] = {};
  const u32* abase = Ad32 + (size_t)(mbase + lrow)*768;
  for (int ks=0; ks<24; ks++){
    int kb = ks*32 + koff;
    u32x8 ld = *(const u32x8*)(abase + kb);
    bf16x8 ah, al;
    #pragma unroll
    for (int j=0;j<8;j++){ ah[j] = (short)(ld[j] & 0xFFFFu); al[j] = (short)(ld[j] >> 16); }
    #pragma unroll
    for (int g=0; g<4; g++){
      bf16x8 bh = *(const bf16x8*)(W_hi + wro[g] + kb);
      bf16x8 bl = *(const bf16x8*)(W_lo + wro[g] + kb);
      acc[g] = __builtin_amdgcn_mfma_f32_16x16x32_bf16(ah, bh, acc[g], 0,0,0);
      acc[g] = __builtin_amdgcn_mfma_f32_16x16x32_bf16(ah, bl, acc[g], 0,0,0);
      acc[g] = __builtin_amdgcn_mfma_f32_16x16x32_bf16(al, bh, acc[g], 0,0,0);
    }
  }
  float bg4[4], w0g[4];
  #pragma unroll
  for (int g=0;g<4;g++){ bg4[g] = b_d[g*H_ + u]; w0g[g] = Wx_d[g*H_ + u]; }
  #pragma unroll
  for (int r=0; r<4; r++){
    int b = mbase + kblk*4 + r;
    float pyb = py[b];
    float gi = acc[0][r] + bg4[0] + pyb*w0g[0];
    float gf = acc[1][r] + bg4[1] + pyb*w0g[1];
    float gg = acc[2][r] + bg4[2] + pyb*w0g[2];
    float go = acc[3][r] + bg4[3] + pyb*w0g[3];
    size_t ci = (size_t)b*H_ + u;
    float cn = sigm(gf)*c_dec[ci] + sigm(gi)*tanhf(gg);
    float hn = sigm(go)*tanhf(cn);
    c_dec[ci] = cn;
    h_dec[ci] = hn;
    AdW[(size_t)b*768 + 512 + u] = packsplit(hn);
  }
}

// ---- enc_proj: ep[bt][64] = eo @ We ----
__global__ __launch_bounds__(256) void gemm_ep(
    const u32* __restrict__ eo32, const u16* __restrict__ Wet_hi, const u16* __restrict__ Wet_lo,
    float* __restrict__ ep)
{
  const int tid = threadIdx.x, wave = tid>>6, lane = tid&63;
  const int lrow = lane&15, kblk = lane>>4, koff = kblk*8;
  const size_t arow = (size_t)blockIdx.x*64 + wave*16 + lrow;
  f32x4 acc[4] = {};
  size_t wro[4];
  #pragma unroll
  for (int nf=0; nf<4; nf++) wro[nf] = (size_t)(nf*16 + lrow)*512;
  for (int ks=0; ks<16; ks++){
    int kb = ks*32 + koff;
    u32x8 ld = *(const u32x8*)(eo32 + arow*512 + kb);
    bf16x8 ah, al;
    #pragma unroll
    for (int j=0;j<8;j++){ ah[j] = (short)(ld[j] & 0xFFFFu); al[j] = (short)(ld[j] >> 16); }
    #pragma unroll
    for (int nf=0; nf<4; nf++){
      bf16x8 bh = *(const bf16x8*)(Wet_hi + wro[nf] + kb);
      bf16x8 bl = *(const bf16x8*)(Wet_lo + wro[nf] + kb);
      acc[nf] = __builtin_amdgcn_mfma_f32_16x16x32_bf16(ah, bh, acc[nf], 0,0,0);
      acc[nf] = __builtin_amdgcn_mfma_f32_16x16x32_bf16(ah, bl, acc[nf], 0,0,0);
      acc[nf] = __builtin_amdgcn_mfma_f32_16x16x32_bf16(al, bh, acc[nf], 0,0,0);
    }
  }
  #pragma unroll
  for (int nf=0; nf<4; nf++)
    #pragma unroll
    for (int r=0; r<4; r++){
      size_t orow = (size_t)blockIdx.x*64 + wave*16 + kblk*4 + r;
      ep[orow*64 + nf*16 + lrow] = acc[nf][r];
    }
}

// ---- generic fp32 SGEMM for small init GEMMs ----
__global__ __launch_bounds__(256) void sgemm_bias(
    const float* __restrict__ A, const float* __restrict__ W,
    const float* __restrict__ bias, float* __restrict__ C,
    int M, int N, int K, int act)
{
  __shared__ float As[64][17];
  __shared__ float Ws[16][64];
  int tid = threadIdx.x;
  int tr = tid >> 4, tc = tid & 15;
  int row0 = blockIdx.y * 64, col0 = blockIdx.x * 64;
  float acc[4][4] = {};
  for (int k0 = 0; k0 < K; k0 += 16) {
    for (int i = tid; i < 64*16; i += 256) {
      int r = i >> 4, kk = i & 15;
      int gr = row0 + r, gk = k0 + kk;
      As[r][kk] = (gr < M && gk < K) ? A[(size_t)gr*K + gk] : 0.f;
    }
    for (int i = tid; i < 16*64; i += 256) {
      int r = i >> 6, c = i & 63;
      int gk = k0 + r, gc = col0 + c;
      Ws[r][c] = (gk < K && gc < N) ? W[(size_t)gk*N + gc] : 0.f;
    }
    __syncthreads();
    #pragma unroll
    for (int kk=0;kk<16;kk++){
      float a0 = As[tr*4+0][kk], a1 = As[tr*4+1][kk];
      float a2v = As[tr*4+2][kk], a3 = As[tr*4+3][kk];
      float4 b4 = *(const float4*)&Ws[kk][tc*4];
      acc[0][0]+=a0*b4.x; acc[0][1]+=a0*b4.y; acc[0][2]+=a0*b4.z; acc[0][3]+=a0*b4.w;
      acc[1][0]+=a1*b4.x; acc[1][1]+=a1*b4.y; acc[1][2]+=a1*b4.z; acc[1][3]+=a1*b4.w;
      acc[2][0]+=a2v*b4.x; acc[2][1]+=a2v*b4.y; acc[2][2]+=a2v*b4.z; acc[2][3]+=a2v*b4.w;
      acc[3][0]+=a3*b4.x; acc[3][1]+=a3*b4.y; acc[3][2]+=a3*b4.z; acc[3][3]+=a3*b4.w;
    }
    __syncthreads();
  }
  #pragma unroll
  for (int i=0;i<4;i++){
    int r = row0 + tr*4 + i; if (r >= M) continue;
    #pragma unroll
    for (int j=0;j<4;j++){
      int c = col0 + tc*4 + j; if (c >= N) continue;
      float vv = acc[i][j] + (bias ? bias[c] : 0.f);
      if (act == 1) vv = tanhf(vv);
      C[(size_t)r*N + c] = vv;
    }
  }
}

// ---- attention step: scores + softmax + wave-split context ----
__global__ __launch_bounds__(256) void attn_step(
    const u32* __restrict__ eo32, const float* __restrict__ ep,
    const float* __restrict__ Wd, const float* __restrict__ v,
    const float* __restrict__ Wo, const float* __restrict__ bo,
    const float* __restrict__ h_dec, u32* __restrict__ Ad32,
    float* __restrict__ py, float* __restrict__ out, int s)
{
  __shared__ float sh_h[256], sh_hwd[64], sh_v[64], sh_sc[256], sh_w[256];
  __shared__ float red4[4][64];
  __shared__ float sh_red[4], sh_red2[4];
  __shared__ float redc[4][512];
  int b = blockIdx.x, tid = threadIdx.x;
  int wave = tid >> 6, lane = tid & 63;
  float hv = h_dec[b*H_ + tid];
  sh_h[tid] = hv;
  if (tid < 64) sh_v[tid] = v[tid];
  __syncthreads();
  if (s > 0) {
    float p = hv * Wo[tid];
    p = wred_sum(p);
    if ((tid & 63) == 0) sh_red[tid>>6] = p;
    __syncthreads();
    if (tid == 0) {
      float y = sh_red[0]+sh_red[1]+sh_red[2]+sh_red[3] + bo[0];
      out[b*HOR_ + (s-1)] = y;
      py[b] = y;
    }
  }
  {
    int a = tid & 63, q = tid >> 6;
    float ssum = 0.f;
    for (int j=q*64; j<q*64+64; j++) ssum += sh_h[j]*Wd[(size_t)j*A_ + a];
    red4[q][a] = ssum;
    __syncthreads();
    if (tid < 64) sh_hwd[tid] = red4[0][tid]+red4[1][tid]+red4[2][tid]+red4[3][tid];
  }
  __syncthreads();
  int aa = tid & 3;
  #pragma unroll
  for (int p=0;p<4;p++){
    int t = p*64 + (tid>>2);
    const float4* ep4 = (const float4*)(ep + ((size_t)(b*T_+t))*A_ + aa*16);
    float partial = 0.f;
    #pragma unroll
    for (int q=0;q<4;q++){
      float4 e4 = ep4[q];
      int a0 = aa*16 + q*4;
      partial += tanhf(e4.x + sh_hwd[a0+0]) * sh_v[a0+0];
      partial += tanhf(e4.y + sh_hwd[a0+1]) * sh_v[a0+1];
      partial += tanhf(e4.z + sh_hwd[a0+2]) * sh_v[a0+2];
      partial += tanhf(e4.w + sh_hwd[a0+3]) * sh_v[a0+3];
    }
    partial += __shfl_xor(partial, 1);
    partial += __shfl_xor(partial, 2);
    if (aa == 0) sh_sc[t] = partial;
  }
  __syncthreads();
  float sc = sh_sc[tid];
  float m = wred_max(sc);
  if ((tid&63)==0) sh_red[tid>>6] = m;
  __syncthreads();
  m = fmaxf(fmaxf(sh_red[0],sh_red[1]), fmaxf(sh_red[2],sh_red[3]));
  float e = expf(sc - m);
  float su = wred_sum(e);
  if ((tid&63)==0) sh_red2[tid>>6] = su;
  __syncthreads();
  su = (sh_red2[0]+sh_red2[1])+(sh_red2[2]+sh_red2[3]);
  sh_w[tid] = e / su;
  __syncthreads();
  // ---- context: wave w owns t in [w*64, w*64+64), 8 cols per lane ----
  float cacc[8] = {};
  const u32* eo = eo32 + (size_t)b*T_*512 + lane*8;
  #pragma unroll 4
  for (int tt=0; tt<64; tt++){
    int t = wave*64 + tt;
    float wgt = sh_w[t];
    u32x4 e0 = *(const u32x4*)(eo + (size_t)t*512);
    u32x4 e1 = *(const u32x4*)(eo + (size_t)t*512 + 4);
    #pragma unroll
    for (int j=0;j<4;j++){
      cacc[j]   += wgt * unpack2f(e0[j]);
      cacc[4+j] += wgt * unpack2f(e1[j]);
    }
  }
  #pragma unroll
  for (int j=0;j<8;j++) redc[wave][lane*8+j] = cacc[j];
  __syncthreads();
  float c0 = redc[0][tid]+redc[1][tid]+redc[2][tid]+redc[3][tid];
  float c1 = redc[0][256+tid]+redc[1][256+tid]+redc[2][256+tid]+redc[3][256+tid];
  Ad32[(size_t)b*768 + tid]       = packsplit(c0);
  Ad32[(size_t)b*768 + 256 + tid] = packsplit(c1);
}

__global__ __launch_bounds__(256) void final_y(const float* __restrict__ h_dec,
    const float* __restrict__ Wo, const float* __restrict__ bo, float* __restrict__ out){
  __shared__ float sh[4];
  int b = blockIdx.x, tid = threadIdx.x;
  float p = h_dec[b*H_+tid]*Wo[tid];
  p = wred_sum(p);
  if ((tid&63)==0) sh[tid>>6]=p;
  __syncthreads();
  if (tid==0) out[b*HOR_ + HOR_-1] = sh[0]+sh[1]+sh[2]+sh[3] + bo[0];
}

__global__ __launch_bounds__(256) void enc_mean_k(const u32* __restrict__ eo32,
                                                  float* __restrict__ em){
  __shared__ float redc[4][512];
  int b = blockIdx.x, tid = threadIdx.x;
  int wave = tid >> 6, lane = tid & 63;
  float cacc[8] = {};
  const u32* eo = eo32 + (size_t)b*T_*512 + lane*8;
  #pragma unroll 4
  for (int tt=0; tt<64; tt++){
    int t = wave*64 + tt;
    u32x4 e0 = *(const u32x4*)(eo + (size_t)t*512);
    u32x4 e1 = *(const u32x4*)(eo + (size_t)t*512 + 4);
    #pragma unroll
    for (int j=0;j<4;j++){ cacc[j] += unpack2f(e0[j]); cacc[4+j] += unpack2f(e1[j]); }
  }
  #pragma unroll
  for (int j=0;j<8;j++) redc[wave][lane*8+j] = cacc[j];
  __syncthreads();
  em[(size_t)b*512 + tid]       = (redc[0][tid]+redc[1][tid]+redc[2][tid]+redc[3][tid])*(1.f/T_);
  em[(size_t)b*512 + 256 + tid] = (redc[0][256+tid]+redc[1][256+tid]+redc[2][256+tid]+redc[3][256+tid])*(1.f/T_);
}

__global__ void pack_hd(const float* __restrict__ hd, u32* __restrict__ Ad32){
  int i = blockIdx.x*256 + threadIdx.x;
  int b = i >> 8, u = i & 255;
  Ad32[(size_t)b*768 + 512 + u] = packsplit(hd[i]);
}

__global__ void py_init(const float* __restrict__ x, float* __restrict__ py){
  int b = blockIdx.x*256 + threadIdx.x;
  if (b < B_)
    py[b] = (x[(size_t)b*T_*F_ + 255*F_ + 0] +
             x[(size_t)b*T_*F_ + 255*F_ + 2]) * 0.5f;
}

extern "C" void kernel_launch(void* const* d_in, const int* in_sizes, int n_in,
                              void* d_out, int out_size, void* d_ws, size_t ws_size,
                              hipStream_t stream)
{
  const float* x    = (const float*)d_in[0];
  const float* W_sp = (const float*)d_in[1];
  const float* b_sp = (const float*)d_in[2];
  const float* Wx_ef= (const float*)d_in[3];
  const float* Wh_ef= (const float*)d_in[4];
  const float* b_ef = (const float*)d_in[5];
  const float* Wx_eb= (const float*)d_in[6];
  const float* Wh_eb= (const float*)d_in[7];
  const float* b_eb = (const float*)d_in[8];
  const float* We   = (const float*)d_in[9];
  const float* Wd   = (const float*)d_in[10];
  const float* v    = (const float*)d_in[11];
  const float* Wx_d = (const float*)d_in[12];
  const float* Wh_d = (const float*)d_in[13];
  const float* b_d  = (const float*)d_in[14];
  const float* W_ih = (const float*)d_in[15];
  const float* b_ih = (const float*)d_in[16];
  const float* W_ic = (const float*)d_in[17];
  const float* b_ic = (const float*)d_in[18];
  const float* Wo   = (const float*)d_in[19];
  const float* bo   = (const float*)d_in[20];
  float* out = (float*)d_out;

  char* base = (char*)d_ws;
  auto alloc = [&](size_t bytes)->char*{
    char* p = base; base += (bytes + 255) & ~(size_t)255; return p;
  };
  u16* Wenc_hi = (u16*)alloc((size_t)2*1024*448*2);
  u16* Wenc_lo = (u16*)alloc((size_t)2*1024*448*2);
  u16* Wdec_hi = (u16*)alloc((size_t)1024*768*2);
  u16* Wdec_lo = (u16*)alloc((size_t)1024*768*2);
  u16* Wet_hi  = (u16*)alloc((size_t)64*512*2);
  u16* Wet_lo  = (u16*)alloc((size_t)64*512*2);
  u32* hsp32   = (u32*)alloc((size_t)T_*B_*DSP_*4);
  u32* hbuf    = (u32*)alloc((size_t)2*2*B_*H_*4);   // [parity][dir][b][u]
  u32* eo32    = (u32*)alloc((size_t)B_*T_*512*4);
  float* em    = (float*)alloc((size_t)B_*512*4);
  float* ep    = (float*)alloc((size_t)B_*T_*64*4);
  float* hd    = (float*)alloc((size_t)B_*H_*4);
  float* cd    = (float*)alloc((size_t)B_*H_*4);
  u32* Ad32    = (u32*)alloc((size_t)B_*768*4);
  float* pyb   = (float*)alloc((size_t)B_*4);
  int* bar     = (int*)alloc((size_t)8*T_*4);
  if ((size_t)(base - (char*)d_ws) > ws_size) return;

  // one-time weight conversions
  conv_w<<<dim3(1792),256,0,stream>>>(Wx_ef, Wh_ef, Wenc_hi, Wenc_lo, DSP_, 448, 1024);
  conv_w<<<dim3(1792),256,0,stream>>>(Wx_eb, Wh_eb, Wenc_hi+458752, Wenc_lo+458752, DSP_, 448, 1024);
  conv_w<<<dim3(3072),256,0,stream>>>(Wx_d+1024, Wh_d, Wdec_hi, Wdec_lo, 512, 768, 1024);
  conv_w<<<dim3(128),256,0,stream>>>(We, We, Wet_hi, Wet_lo, 512, 512, 64);

  spatial_proj<<<dim3(256),192,0,stream>>>(x, W_sp, b_sp, hsp32);

  hipMemsetAsync(hbuf, 0, (size_t)2*B_*H_*4, stream);   // parity-0 h = 0
  hipMemsetAsync(bar, 0, (size_t)8*T_*4, stream);       // group barrier slots

  enc_scan<<<dim3(ENC_NBLK), dim3(256), 2*4*16*WSTR*2, stream>>>(
      hsp32, Wenc_hi, Wenc_lo, b_ef, b_eb, hbuf, eo32, bar);

  enc_mean_k<<<dim3(256),256,0,stream>>>(eo32, em);
  sgemm_bias<<<dim3(4,4),256,0,stream>>>(em, W_ih, b_ih, hd, B_, H_, 2*H_, 1);
  sgemm_bias<<<dim3(4,4),256,0,stream>>>(em, W_ic, b_ic, cd, B_, H_, 2*H_, 1);
  pack_hd<<<dim3(256),256,0,stream>>>(hd, Ad32);
  gemm_ep<<<dim3(1024),256,0,stream>>>(eo32, Wet_hi, Wet_lo, ep);
  py_init<<<dim3(1),256,0,stream>>>(x, pyb);

  for (int s=0; s<HOR_; s++){
    attn_step<<<dim3(256),256,0,stream>>>(eo32, ep, Wd, v, Wo, bo, hd, Ad32, pyb, out, s);
    dec_step_mfma<<<dim3(16,8),128,0,stream>>>(Ad32, Wdec_hi, Wdec_lo, b_d, Wx_d, pyb, cd, hd, Ad32);
  }
  final_y<<<dim3(256),256,0,stream>>>(hd, Wo, bo, out);
}